// Round 9
// baseline (166.595 us; speedup 1.0000x reference)
//
#include <hip/hip_runtime.h>

// Problem constants
#define DD 64
#define LL 50
#define NB 4096
#define NT 100

typedef __attribute__((ext_vector_type(8))) __bf16 bf16x8;
typedef __attribute__((ext_vector_type(4))) float f32x4;

__device__ __forceinline__ float sigmoidf_(float x) {
    return __builtin_amdgcn_rcpf(1.0f + __expf(-x));
}
// round-half-up f32->bf16 pack (table-pack path, numerics match prior k0)
__device__ __forceinline__ unsigned pack_bf16(float hi, float lo) {
    union { float f; unsigned u; } a, b;
    a.f = hi; b.f = lo;
    return ((a.u + 0x8000u) & 0xffff0000u) | ((b.u + 0x8000u) >> 16);
}
__device__ __forceinline__ uint4 cvt8u(const float* f) {
    uint4 r;
    r.x = pack_bf16(f[1], f[0]);
    r.y = pack_bf16(f[3], f[2]);
    r.z = pack_bf16(f[5], f[4]);
    r.w = pack_bf16(f[7], f[6]);
    return r;
}
// HW packed RNE convert: dst.lo = bf16(lo), dst.hi = bf16(hi)
__device__ __forceinline__ unsigned cvtpk(float lo, float hi) {
    unsigned r;
    asm("v_cvt_pk_bf16_f32 %0, %1, %2" : "=v"(r) : "v"(lo), "v"(hi));
    return r;
}
__device__ __forceinline__ bf16x8 cvt8f(const float* f) {
    uint4 r;
    r.x = cvtpk(f[0], f[1]);
    r.y = cvtpk(f[2], f[3]);
    r.z = cvtpk(f[4], f[5]);
    r.w = cvtpk(f[6], f[7]);
    return __builtin_bit_cast(bf16x8, r);
}
// async global->LDS: wave-uniform LDS base + lane*size (gfx950)
__device__ __forceinline__ void glds16(const void* g, void* l) {
    __builtin_amdgcn_global_load_lds(
        (const __attribute__((address_space(1))) void*)g,
        (__attribute__((address_space(3))) void*)l, 16, 0, 0);
}
__device__ __forceinline__ void glds4(const void* g, void* l) {
    __builtin_amdgcn_global_load_lds(
        (const __attribute__((address_space(1))) void*)g,
        (__attribute__((address_space(3))) void*)l, 4, 0, 0);
}

// ===========================================================================
// K_PACK: ONE block. Packs the small weight tables to bf16 workspace:
//   wiB[64][64]  = bf16(fg_item_W)                (k1 B-frags for the gate GEMM)
//   wuB[128][64] = bf16([fg_user_W ; igu^T ; 0])  (k1 in-block ufg/t2 GEMM)
//   bias[64]     = fg_user_b + fg_item_b
// Replaces the old 257-block k0 (user GEMM + 2MB ufg/t2 workspace round-trip):
// each k1 block now computes its own ufg/t2 with 10 MFMAs on the idle matrix
// pipe (A = broadcast user row).
// ===========================================================================
__global__ __launch_bounds__(256) void k_pack(
    const float* __restrict__ Wi, const float* __restrict__ Wu,
    const float* __restrict__ bu, const float* __restrict__ bi,
    const float* __restrict__ igu,
    unsigned short* __restrict__ wiB, unsigned short* __restrict__ wuB,
    float* __restrict__ biasArr)
{
    __shared__ float sT[64][52];   // igu rows (pad 52 to spread banks)
    const int tid = threadIdx.x;
    const int g = tid >> 6, n = tid & 63;

    if (g == 0) {                  // Wi row n -> wiB[n]
        float tmp[64];
#pragma unroll
        for (int c4 = 0; c4 < 16; c4++)
            *(float4*)&tmp[c4 * 4] = *(const float4*)(Wi + n * DD + c4 * 4);
#pragma unroll
        for (int ch = 0; ch < 8; ch++)
            *(uint4*)(wiB + n * DD + ch * 8) = cvt8u(tmp + ch * 8);
    } else if (g == 1) {           // Wu row n -> wuB[n]
        float tmp[64];
#pragma unroll
        for (int c4 = 0; c4 < 16; c4++)
            *(float4*)&tmp[c4 * 4] = *(const float4*)(Wu + n * DD + c4 * 4);
#pragma unroll
        for (int ch = 0; ch < 8; ch++)
            *(uint4*)(wuB + n * DD + ch * 8) = cvt8u(tmp + ch * 8);
    } else if (g == 2) {           // igu row k=n (50 f32, unaligned) -> LDS
#pragma unroll
        for (int l = 0; l < LL; l++) sT[n][l] = igu[n * LL + l];
    } else {                       // bias
        biasArr[n] = bu[n] + bi[n];
    }
    __syncthreads();
    if (g == 2 && n < LL) {        // igu column n -> wuB[64+n] (igu^T row)
        float tmp[64];
#pragma unroll
        for (int k = 0; k < 64; k++) tmp[k] = sT[k][n];
#pragma unroll
        for (int ch = 0; ch < 8; ch++)
            *(uint4*)(wuB + (64 + n) * DD + ch * 8) = cvt8u(tmp + ch * 8);
    }
    if (g == 3 && n < 14) {        // zero-pad rows 114..127 (t2 cols 50..63)
        const uint4 z = {0u, 0u, 0u, 0u};
#pragma unroll
        for (int ch = 0; ch < 8; ch++)
            *(uint4*)(wuB + (114 + n) * DD + ch * 8) = z;
    }
}

// ===========================================================================
// K1F v6: R3 wave-decoupled structure + IN-BLOCK ufg/t2.
//   Phase A per wave: 4 item glds16 (XOR-swizzled, wave-private quadrant),
//   7 W2 float4 -> regs, u A-frags (broadcast row) + 10 wuB B-frags + 4 bias
//   (all L2-hot), sUu/b2 glds4 -> s_waitcnt vmcnt(0) (wave-local, no barrier).
//   Then 10 MFMAs compute ufg[64] (redundant per wave -> no cross-wave dep,
//   no extra barrier) + this wave's t2[16] in-register; then the main union
//   MFMAs + fused epilogue. 2 barriers total, same as R3.
// ===========================================================================
__global__ __launch_bounds__(256, 4) void k1_fused(
    const int* __restrict__ uid_g, const int* __restrict__ iid_g,
    const int* __restrict__ tgt_g,
    const float* __restrict__ user_table, const float* __restrict__ item_table,
    const float* __restrict__ W2, const float* __restrict__ b2,
    const unsigned short* __restrict__ wiB, const unsigned short* __restrict__ wuB,
    const float* __restrict__ biasArr, const float* __restrict__ igi,
    float* __restrict__ out)
{
    const int tid = threadIdx.x;
    const int lane = tid & 63;
    const int w = tid >> 6;                 // wave id 0..3 == union mi
    const int c = lane & 15, q = lane >> 4;
    const int j = tid & 15, gg = tid >> 4;  // scoring: 16 groups of 16 lanes
    const int b = blockIdx.x;

    __shared__ __align__(16) float sE[4][16 * DD];  // wave-private item quadrants
    __shared__ __align__(16) float sB[128];         // b2 staged
    __shared__ __align__(16) float sUu[DD];         // user row
    __shared__ __align__(16) float sU[4 * DD];      // per-wave unum partials
    __shared__ __align__(16) float sS[4 * DD];      // per-wave sip partials
    __shared__ float sI[4];                         // per-wave isum partials
    __shared__ float sOut[112];

    const int* iidp = iid_g + b * LL;
    const int* tgtp = tgt_g + b * NT;
    float* sEw = sE[w];
    const int uid = uid_g[b];               // block-uniform -> scalar load

    // ---- item ids for THIS wave's 16 rows (clamped) ----
    int iid4[4];
#pragma unroll
    for (int s = 0; s < 4; s++) {
        const int r = w * 16 + 4 * s + q;
        iid4[s] = iidp[r < LL ? r : LL - 1];
    }
    // ---- tgt ids (group-major, for W2 prefetch) ----
    int tt[7];
#pragma unroll
    for (int i = 0; i < 7; i++) {
        const int ts = i * 16 + gg;             // 0..111 (100..111 = pad)
        tt[i] = tgtp[ts < NT ? ts : NT - 1];
    }

    // ---- async item gather into own quadrant (XOR-swizzled chunks) ----
#pragma unroll
    for (int s = 0; s < 4; s++) {
        const int rl = 4 * s + q;
        const int j2 = c ^ (rl & 7);
        glds16(item_table + (size_t)iid4[s] * DD + j2 * 4, sEw + s * 256);
    }

    // ---- W2 prefetch to regs ----
    float4 wv[7];
#pragma unroll
    for (int i = 0; i < 7; i++)
        wv[i] = *(const float4*)(W2 + (size_t)tt[i] * DD + j * 4);

    // ---- small staged loads, spread across waves ----
    if (w == 1)
        glds4(user_table + (size_t)uid * DD + lane, sUu);
    if (w == 2) {
        const int tb = lane < NT ? lane : NT - 1;
        glds4(b2 + tgtp[tb], sB);
    }
    if (w == 3) {
        const int sl = 64 + lane;
        const int tb = sl < NT ? sl : NT - 1;
        glds4(b2 + tgtp[tb], sB + 64);
    }

    // ---- u A-frags (broadcast: every output row = u) ----
    const float* urow = user_table + (size_t)uid * DD;
    bf16x8 af[2];
#pragma unroll
    for (int kf = 0; kf < 2; kf++) {
        float tmp[8];
        *(float4*)&tmp[0] = *(const float4*)(urow + kf * 32 + q * 8);
        *(float4*)&tmp[4] = *(const float4*)(urow + kf * 32 + q * 8 + 4);
        af[kf] = cvt8f(tmp);
    }
    // ---- wuB frags: 4 ufg col-groups + this wave's t2 col-group (L2-hot) ----
    bf16x8 wg5[5][2];
#pragma unroll
    for (int ng = 0; ng < 5; ng++) {
        const int row = (ng < 4) ? (ng * 16 + c) : (64 + w * 16 + c);
#pragma unroll
        for (int kf = 0; kf < 2; kf++)
            wg5[ng][kf] = __builtin_bit_cast(bf16x8,
                *(const uint4*)(wuB + row * DD + kf * 32 + q * 8));
    }
    float biasv[4];
#pragma unroll
    for (int ni = 0; ni < 4; ni++) biasv[ni] = biasArr[ni * 16 + c];

    float igi4[4];
#pragma unroll
    for (int ni = 0; ni < 4; ni++) igi4[ni] = igi[ni * 16 + c];

    // ---- wb frags (8 KB table, L2-hot) ----
    bf16x8 wb[4][2];
#pragma unroll
    for (int ni = 0; ni < 4; ni++)
#pragma unroll
        for (int kf = 0; kf < 2; kf++)
            wb[ni][kf] = __builtin_bit_cast(bf16x8,
                *(const uint4*)(wiB + (ni * 16 + c) * DD + kf * 32 + q * 8));

    // ---- wave-local drain: own glds + all reg loads complete; no barrier ----
    asm volatile("s_waitcnt vmcnt(0)" ::: "memory");
    __builtin_amdgcn_sched_barrier(0);

    // ---- in-register ufg/t2 via MFMA (A rows identical -> use reg 0) ----
    float ufg4[4], t2val;
    {
        f32x4 fa[5];
#pragma unroll
        for (int ng = 0; ng < 5; ng++) {
            f32x4 a = {0.f, 0.f, 0.f, 0.f};
            a = __builtin_amdgcn_mfma_f32_16x16x32_bf16(af[0], wg5[ng][0], a, 0, 0, 0);
            a = __builtin_amdgcn_mfma_f32_16x16x32_bf16(af[1], wg5[ng][1], a, 0, 0, 0);
            fa[ng] = a;
        }
#pragma unroll
        for (int ni = 0; ni < 4; ni++) ufg4[ni] = fa[ni][0] + biasv[ni];
        t2val = fa[4][0];                   // lane holds t2[w*16 + c]
    }
    float t2a[4];
#pragma unroll
    for (int reg = 0; reg < 4; reg++) t2a[reg] = __shfl(t2val, q * 4 + reg);

    // ---- A-frags from own quadrant (deswizzled), invalid rows zeroed ----
    bf16x8 ea[2];
    {
        const int grow = w * 16 + c;
        const float* rowp = sEw + c * DD;
        const int s7 = c & 7;
#pragma unroll
        for (int kf = 0; kf < 2; kf++) {
            float tmp[8];
            const int ch0 = (kf * 8 + 2 * q) ^ s7;
            const int ch1 = (kf * 8 + 2 * q + 1) ^ s7;
            *(float4*)&tmp[0] = *(const float4*)(rowp + ch0 * 4);
            *(float4*)&tmp[4] = *(const float4*)(rowp + ch1 * 4);
            if (grow >= LL) {
#pragma unroll
                for (int i = 0; i < 8; i++) tmp[i] = 0.f;
            }
            ea[kf] = cvt8f(tmp);
        }
    }

    // ---- union MFMA + fused per-reg epilogue (all reads wave-private) ----
    float unum[4] = {0.f, 0.f, 0.f, 0.f};
    float sip[4]  = {0.f, 0.f, 0.f, 0.f};
    float isum = 0.f;
    {
        f32x4 acc[4];
#pragma unroll
        for (int ni = 0; ni < 4; ni++) {
            f32x4 a = {0.f, 0.f, 0.f, 0.f};
            a = __builtin_amdgcn_mfma_f32_16x16x32_bf16(ea[0], wb[ni][0], a, 0, 0, 0);
            a = __builtin_amdgcn_mfma_f32_16x16x32_bf16(ea[1], wb[ni][1], a, 0, 0, 0);
            acc[ni] = a;
        }
#pragma unroll
        for (int reg = 0; reg < 4; reg++) {
            const int lrl = q * 4 + reg;            // local row in quadrant
            const int valid = (w * 16 + lrl < LL);
            const int s7 = lrl & 7;
            float gd[4];
            float t1 = 0.f;
#pragma unroll
            for (int ni = 0; ni < 4; ni++) {
                const int phys = (4 * ni + (c >> 2)) ^ s7;
                const float ev = sEw[lrl * DD + phys * 4 + (c & 3)];
                const float e = valid ? ev : 0.f;
                const float g = sigmoidf_(acc[ni][reg] + ufg4[ni]);
                gd[ni] = e * g;
                t1 += gd[ni] * igi4[ni];
                sip[ni] += e;
            }
            t1 += __shfl_xor(t1, 1); t1 += __shfl_xor(t1, 2);
            t1 += __shfl_xor(t1, 4); t1 += __shfl_xor(t1, 8);
            const float inst = valid ? sigmoidf_(t1 + t2a[reg]) : 0.f;
            isum += inst;
#pragma unroll
            for (int ni = 0; ni < 4; ni++)
                unum[ni] += gd[ni] * inst;
        }
    }

    // intra-wave: sum over q groups, then pick ni == q -> value for d = lane
#pragma unroll
    for (int ni = 0; ni < 4; ni++) {
        unum[ni] += __shfl_xor(unum[ni], 16); unum[ni] += __shfl_xor(unum[ni], 32);
        sip[ni]  += __shfl_xor(sip[ni], 16);  sip[ni]  += __shfl_xor(sip[ni], 32);
    }
    isum += __shfl_xor(isum, 16); isum += __shfl_xor(isum, 32);

    const float un = (q == 0) ? unum[0] : (q == 1) ? unum[1] : (q == 2) ? unum[2] : unum[3];
    const float si = (q == 0) ? sip[0]  : (q == 1) ? sip[1]  : (q == 2) ? sip[2]  : sip[3];
    sU[w * DD + lane] = un;
    sS[w * DD + lane] = si;
    if (lane == 0) sI[w] = isum;
    __syncthreads();   // barrier 1: cross-wave reduce (also orders sUu/sB)

    // ---- redundant all-thread reduce -> vr (user-vector slice dims j*4..) ----
    float4 vr;
    {
        const float4 u0 = *(const float4*)&sU[0 * DD + j * 4];
        const float4 u1 = *(const float4*)&sU[1 * DD + j * 4];
        const float4 u2 = *(const float4*)&sU[2 * DD + j * 4];
        const float4 u3 = *(const float4*)&sU[3 * DD + j * 4];
        const float4 s0 = *(const float4*)&sS[0 * DD + j * 4];
        const float4 s1 = *(const float4*)&sS[1 * DD + j * 4];
        const float4 s2 = *(const float4*)&sS[2 * DD + j * 4];
        const float4 s3 = *(const float4*)&sS[3 * DD + j * 4];
        const float4 uu = *(const float4*)&sUu[j * 4];
        const float rist = __builtin_amdgcn_rcpf(sI[0] + sI[1] + sI[2] + sI[3]);
        vr.x = uu.x + (u0.x + u1.x + u2.x + u3.x) * rist + (s0.x + s1.x + s2.x + s3.x);
        vr.y = uu.y + (u0.y + u1.y + u2.y + u3.y) * rist + (s0.y + s1.y + s2.y + s3.y);
        vr.z = uu.z + (u0.z + u1.z + u2.z + u3.z) * rist + (s0.z + s1.z + s2.z + s3.z);
        vr.w = uu.w + (u0.w + u1.w + u2.w + u3.w) * rist + (s0.w + s1.w + s2.w + s3.w);
    }

    // ---- scoring from prefetched registers ----
#pragma unroll
    for (int i = 0; i < 7; i++) {
        const int ts = i * 16 + gg;
        float s = wv[i].x * vr.x + wv[i].y * vr.y + wv[i].z * vr.z + wv[i].w * vr.w;
        s += __shfl_xor(s, 1); s += __shfl_xor(s, 2);
        s += __shfl_xor(s, 4); s += __shfl_xor(s, 8);
        if (j == 0 && ts < NT) sOut[ts] = s + sB[ts];
    }
    __syncthreads();   // barrier 2: sOut staging
    if (tid < NT) out[b * NT + tid] = sOut[tid];
}

// ===========================================================================
extern "C" void kernel_launch(void* const* d_in, const int* in_sizes, int n_in,
                              void* d_out, int out_size, void* d_ws, size_t ws_size,
                              hipStream_t stream)
{
    const int* user_ids        = (const int*)d_in[0];
    const int* item_seq_ids    = (const int*)d_in[1];
    const int* target_item_ids = (const int*)d_in[2];
    const float* user_tab      = (const float*)d_in[3];
    const float* item_tab      = (const float*)d_in[4];
    const float* W2_tab        = (const float*)d_in[5];
    const float* b2_tab        = (const float*)d_in[6];
    const float* fg_item_W     = (const float*)d_in[7];
    const float* fg_item_b     = (const float*)d_in[8];
    const float* fg_user_W     = (const float*)d_in[9];
    const float* fg_user_b     = (const float*)d_in[10];
    const float* igi           = (const float*)d_in[11];
    const float* igu           = (const float*)d_in[12];
    float* out = (float*)d_out;

    unsigned short* wiB_ws  = (unsigned short*)d_ws;        // [64][64] bf16
    unsigned short* wuB_ws  = wiB_ws + 64 * 64;             // [128][64] bf16
    float* bias_ws          = (float*)(wuB_ws + 128 * 64);  // [64] f32

    k_pack<<<1, 256, 0, stream>>>(fg_item_W, fg_user_W, fg_user_b, fg_item_b,
                                  igu, wiB_ws, wuB_ws, bias_ws);
    k1_fused<<<NB, 256, 0, stream>>>(user_ids, item_seq_ids, target_item_ids,
                                     user_tab, item_tab, W2_tab, b2_tab,
                                     wiB_ws, wuB_ws, bias_ws, igi, out);
}

// Round 10
// 155.123 us; speedup vs baseline: 1.0740x; 1.0740x over previous
//
#include <hip/hip_runtime.h>

// Problem constants
#define DD 64
#define LL 50
#define NB 4096
#define NT 100

typedef __attribute__((ext_vector_type(8))) __bf16 bf16x8;
typedef __attribute__((ext_vector_type(4))) float f32x4;

__device__ __forceinline__ float sigmoidf_(float x) {
    // v_rcp_f32 (~1ulp) instead of precise-division sequence
    return __builtin_amdgcn_rcpf(1.0f + __expf(-x));
}
// round-half-up f32->bf16, pack two into one u32 (hi -> upper 16)  [k0 path]
__device__ __forceinline__ unsigned pack_bf16(float hi, float lo) {
    union { float f; unsigned u; } a, b;
    a.f = hi; b.f = lo;
    return ((a.u + 0x8000u) & 0xffff0000u) | ((b.u + 0x8000u) >> 16);
}
__device__ __forceinline__ uint4 cvt8u(const float* f) {
    uint4 r;
    r.x = pack_bf16(f[1], f[0]);
    r.y = pack_bf16(f[3], f[2]);
    r.z = pack_bf16(f[5], f[4]);
    r.w = pack_bf16(f[7], f[6]);
    return r;
}
__device__ __forceinline__ bf16x8 cvt8(const float* f) {
    return __builtin_bit_cast(bf16x8, cvt8u(f));
}
// HW packed RNE convert: dst.lo = bf16(lo), dst.hi = bf16(hi)  [k1 path]
__device__ __forceinline__ unsigned cvtpk(float lo, float hi) {
    unsigned r;
    asm("v_cvt_pk_bf16_f32 %0, %1, %2" : "=v"(r) : "v"(lo), "v"(hi));
    return r;
}
__device__ __forceinline__ bf16x8 cvt8f(const float* f) {
    uint4 r;
    r.x = cvtpk(f[0], f[1]);
    r.y = cvtpk(f[2], f[3]);
    r.z = cvtpk(f[4], f[5]);
    r.w = cvtpk(f[6], f[7]);
    return __builtin_bit_cast(bf16x8, r);
}
// async global->LDS: wave-uniform LDS base + lane*size (gfx950)
__device__ __forceinline__ void glds16(const float* g, float* l) {
    __builtin_amdgcn_global_load_lds(
        (const __attribute__((address_space(1))) void*)g,
        (__attribute__((address_space(3))) void*)l, 16, 0, 0);
}
__device__ __forceinline__ void glds4(const float* g, float* l) {
    __builtin_amdgcn_global_load_lds(
        (const __attribute__((address_space(1))) void*)g,
        (__attribute__((address_space(3))) void*)l, 4, 0, 0);
}

// ===========================================================================
// K0 v2: blocks 0..255: batched user GEMM, 16 users/block, now 4 WAVES
//   (wave wv owns ni = 2*wv, 2*wv+1 -> half the serial chain of R3's 2-wave
//   version).  igu (12.8 KB, contiguous) is staged into LDS with coalesced
//   loads; the t2 B-frags become 2-cycle ds_reads instead of the 32 strided
//   (200 B) scalar gathers per lane that dominated R3's k0 (~11 us).
//   block 256: pack fg_item_W -> bf16 (wave 0 only).  Numerics identical
//   to R3 (same cvt8 round-half-up, igu values pass through LDS unchanged).
// ===========================================================================
__global__ __launch_bounds__(256) void k0_user(
    const int* __restrict__ uid_g, const float* __restrict__ user_table,
    const float* __restrict__ Wu, const float* __restrict__ bu,
    const float* __restrict__ bi, const float* __restrict__ igu,
    const float* __restrict__ Wi,
    float* __restrict__ ufg_ws, float* __restrict__ t2_ws,
    unsigned short* __restrict__ wiB_ws)
{
    if (blockIdx.x == 256) {   // Wi -> bf16 pack (one wave only)
        if (threadIdx.x >= 64) return;
        const int n = threadIdx.x;
        float tmp[64];
#pragma unroll
        for (int c4 = 0; c4 < 16; c4++)
            *(float4*)&tmp[c4 * 4] = *(const float4*)(Wi + n * DD + c4 * 4);
#pragma unroll
        for (int ch = 0; ch < 8; ch++)
            *(uint4*)(wiB_ws + n * DD + ch * 8) = cvt8u(tmp + ch * 8);
        return;
    }

    __shared__ float sIgu[64][52];          // igu[k][l], pad 52
    const int tid = threadIdx.x;
    const int lane = tid & 63;
    const int wv = tid >> 6;                // wave 0..3 -> ni = 2*wv, 2*wv+1
    const int c = lane & 15, q = lane >> 4;

    // ---- coalesced igu staging: 3200 contiguous f32 -> LDS [k][l] ----
    for (int e = tid; e < 64 * LL; e += 256)
        sIgu[e / LL][e % LL] = igu[e];

    // ---- user A-frags (all 4 waves identical; L2-absorbed redundancy) ----
    const int uid = uid_g[blockIdx.x * 16 + c];
    const float* urow = user_table + (size_t)uid * DD;
    bf16x8 af[2];
#pragma unroll
    for (int kf = 0; kf < 2; kf++) {
        float tmp[8];
        *(float4*)&tmp[0] = *(const float4*)(urow + kf * 32 + q * 8);
        *(float4*)&tmp[4] = *(const float4*)(urow + kf * 32 + q * 8 + 4);
        af[kf] = cvt8(tmp);
    }

    __syncthreads();   // sIgu ready

#pragma unroll
    for (int ni0 = 0; ni0 < 2; ni0++) {
        const int ni = wv * 2 + ni0;
        f32x4 a = {0.f, 0.f, 0.f, 0.f};
#pragma unroll
        for (int kf = 0; kf < 2; kf++) {
            const int k0 = kf * 32 + q * 8;
            float tmp[8];
            if (ni < 4) {
                const float* src = Wu + (ni * 16 + c) * DD + k0;
                *(float4*)&tmp[0] = *(const float4*)src;
                *(float4*)&tmp[4] = *(const float4*)(src + 4);
            } else {
                const int l = ni * 16 + c - 64;
#pragma unroll
                for (int jj = 0; jj < 8; jj++)
                    tmp[jj] = (l < LL) ? sIgu[k0 + jj][l] : 0.f;
            }
            a = __builtin_amdgcn_mfma_f32_16x16x32_bf16(af[kf], cvt8(tmp), a, 0, 0, 0);
        }
        const int n = ni * 16 + c;
#pragma unroll
        for (int reg = 0; reg < 4; reg++) {
            const int bo = blockIdx.x * 16 + q * 4 + reg;
            if (n < DD)           ufg_ws[bo * DD + n] = a[reg] + bu[n] + bi[n];
            else if (n < DD + LL) t2_ws[bo * DD + (n - DD)] = a[reg];
        }
    }
}

// ===========================================================================
// K1F (EXACT R3 code, proven 41.5us): fused union + scoring; wave-decoupled
//   phases A/B.  Wave w only touches item rows w*16..w*16+15 -> item tile is
//   wave-PRIVATE.  Each wave: issue own 4 glds16 + W2 regs + t2 float4 +
//   wb/scalars, asm s_waitcnt vmcnt(0) + sched_barrier(0), then phase B
//   independently.  2 barriers: cross-wave reduce, sOut staging.
// ===========================================================================
__global__ __launch_bounds__(256, 4) void k1_fused(
    const int* __restrict__ uid_g, const int* __restrict__ iid_g,
    const int* __restrict__ tgt_g,
    const float* __restrict__ user_table, const float* __restrict__ item_table,
    const float* __restrict__ W2, const float* __restrict__ b2,
    const unsigned short* __restrict__ wiB, const float* __restrict__ igi,
    const float* __restrict__ ufg_ws, const float* __restrict__ t2_ws,
    float* __restrict__ out)
{
    const int tid = threadIdx.x;
    const int lane = tid & 63;
    const int w = tid >> 6;                 // wave id 0..3 == union mi
    const int c = lane & 15, q = lane >> 4;
    const int j = tid & 15, gg = tid >> 4;  // scoring: 16 groups of 16 lanes
    const int b = blockIdx.x;

    __shared__ __align__(16) float sE[4][16 * DD];  // wave-private item quadrants
    __shared__ __align__(16) float sB[128];         // b2 staged
    __shared__ __align__(16) float sUu[DD];         // user row
    __shared__ __align__(16) float sU[4 * DD];      // per-wave unum partials
    __shared__ __align__(16) float sS[4 * DD];      // per-wave sip partials
    __shared__ float sI[4];                         // per-wave isum partials
    __shared__ float sOut[112];

    const int* iidp = iid_g + b * LL;
    const int* tgtp = tgt_g + b * NT;
    float* sEw = sE[w];

    // ---- item ids for THIS wave's 16 rows (clamped) ----
    int iid4[4];
#pragma unroll
    for (int s = 0; s < 4; s++) {
        const int r = w * 16 + 4 * s + (lane >> 4);
        iid4[s] = iidp[r < LL ? r : LL - 1];
    }
    // ---- tgt ids (group-major, for W2 prefetch) ----
    int tt[7];
#pragma unroll
    for (int i = 0; i < 7; i++) {
        const int ts = i * 16 + gg;             // 0..111 (100..111 = pad)
        tt[i] = tgtp[ts < NT ? ts : NT - 1];
    }

    // ---- async item gather into own quadrant: local rows 4s..4s+3, 16B
    //      chunks XOR-swizzled by (local_row & 7) ----
#pragma unroll
    for (int s = 0; s < 4; s++) {
        const int rl = 4 * s + (lane >> 4);
        const int j2 = (lane & 15) ^ (rl & 7);
        glds16(item_table + (size_t)iid4[s] * DD + j2 * 4, sEw + s * 256);
    }

    // ---- W2 prefetch to regs (pinned before the waitcnt below) ----
    float4 wv[7];
#pragma unroll
    for (int i = 0; i < 7; i++)
        wv[i] = *(const float4*)(W2 + (size_t)tt[i] * DD + j * 4);

    // ---- small staged loads, spread across waves ----
    if (w == 1) {
        const int uid = uid_g[b];
        glds4(user_table + (size_t)uid * DD + lane, sUu);
    }
    if (w == 2) {
        const int tb = lane < NT ? lane : NT - 1;
        glds4(b2 + tgtp[tb], sB);
    }
    if (w == 3) {
        const int sl = 64 + lane;
        const int tb = sl < NT ? sl : NT - 1;
        glds4(b2 + tgtp[tb], sB + 64);
    }

    // ---- per-b scalars + t2 slice (float4, no LDS round-trip) ----
    float ufg4[4], igi4[4];
#pragma unroll
    for (int ni = 0; ni < 4; ni++) {
        ufg4[ni] = ufg_ws[b * DD + ni * 16 + c];
        igi4[ni] = igi[ni * 16 + c];
    }
    const float4 t2v = *(const float4*)(t2_ws + b * DD + w * 16 + q * 4);
    float t2a[4] = {t2v.x, t2v.y, t2v.z, t2v.w};

    // ---- wb frags (8 KB table, L2-hot) ----
    bf16x8 wb[4][2];
#pragma unroll
    for (int ni = 0; ni < 4; ni++)
#pragma unroll
        for (int kf = 0; kf < 2; kf++)
            wb[ni][kf] = __builtin_bit_cast(bf16x8,
                *(const uint4*)(wiB + (ni * 16 + c) * DD + kf * 32 + q * 8));

    // ---- wave-local drain: own glds + all reg loads complete; no barrier ----
    asm volatile("s_waitcnt vmcnt(0)" ::: "memory");
    __builtin_amdgcn_sched_barrier(0);

    // ---- A-frags from own quadrant (deswizzled), invalid rows zeroed ----
    bf16x8 ea[2];
    {
        const int grow = w * 16 + c;
        const float* rowp = sEw + c * DD;
        const int s7 = c & 7;
#pragma unroll
        for (int kf = 0; kf < 2; kf++) {
            float tmp[8];
            const int ch0 = (kf * 8 + 2 * q) ^ s7;
            const int ch1 = (kf * 8 + 2 * q + 1) ^ s7;
            *(float4*)&tmp[0] = *(const float4*)(rowp + ch0 * 4);
            *(float4*)&tmp[4] = *(const float4*)(rowp + ch1 * 4);
            if (grow >= LL) {
#pragma unroll
                for (int i = 0; i < 8; i++) tmp[i] = 0.f;
            }
            ea[kf] = cvt8f(tmp);
        }
    }

    // ---- union MFMA + fused per-reg epilogue (all reads wave-private) ----
    float unum[4] = {0.f, 0.f, 0.f, 0.f};
    float sip[4]  = {0.f, 0.f, 0.f, 0.f};
    float isum = 0.f;
    {
        f32x4 acc[4];
#pragma unroll
        for (int ni = 0; ni < 4; ni++) {
            f32x4 a = {0.f, 0.f, 0.f, 0.f};
            a = __builtin_amdgcn_mfma_f32_16x16x32_bf16(ea[0], wb[ni][0], a, 0, 0, 0);
            a = __builtin_amdgcn_mfma_f32_16x16x32_bf16(ea[1], wb[ni][1], a, 0, 0, 0);
            acc[ni] = a;
        }
#pragma unroll
        for (int reg = 0; reg < 4; reg++) {
            const int lrl = q * 4 + reg;            // local row in quadrant
            const int valid = (w * 16 + lrl < LL);
            const int s7 = lrl & 7;
            float gd[4];
            float t1 = 0.f;
#pragma unroll
            for (int ni = 0; ni < 4; ni++) {
                const int phys = (4 * ni + (c >> 2)) ^ s7;
                const float ev = sEw[lrl * DD + phys * 4 + (c & 3)];
                const float e = valid ? ev : 0.f;
                const float g = sigmoidf_(acc[ni][reg] + ufg4[ni]);
                gd[ni] = e * g;
                t1 += gd[ni] * igi4[ni];
                sip[ni] += e;
            }
            t1 += __shfl_xor(t1, 1); t1 += __shfl_xor(t1, 2);
            t1 += __shfl_xor(t1, 4); t1 += __shfl_xor(t1, 8);
            const float inst = valid ? sigmoidf_(t1 + t2a[reg]) : 0.f;
            isum += inst;
#pragma unroll
            for (int ni = 0; ni < 4; ni++)
                unum[ni] += gd[ni] * inst;
        }
    }

    // intra-wave: sum over q groups, then pick ni == q -> value for d = lane
#pragma unroll
    for (int ni = 0; ni < 4; ni++) {
        unum[ni] += __shfl_xor(unum[ni], 16); unum[ni] += __shfl_xor(unum[ni], 32);
        sip[ni]  += __shfl_xor(sip[ni], 16);  sip[ni]  += __shfl_xor(sip[ni], 32);
    }
    isum += __shfl_xor(isum, 16); isum += __shfl_xor(isum, 32);

    const float un = (q == 0) ? unum[0] : (q == 1) ? unum[1] : (q == 2) ? unum[2] : unum[3];
    const float si = (q == 0) ? sip[0]  : (q == 1) ? sip[1]  : (q == 2) ? sip[2]  : sip[3];
    sU[w * DD + lane] = un;
    sS[w * DD + lane] = si;
    if (lane == 0) sI[w] = isum;
    __syncthreads();   // barrier 1: cross-wave reduce (also orders sUu/sB)

    // ---- redundant all-thread reduce -> vr (user-vector slice dims j*4..) ----
    float4 vr;
    {
        const float4 u0 = *(const float4*)&sU[0 * DD + j * 4];
        const float4 u1 = *(const float4*)&sU[1 * DD + j * 4];
        const float4 u2 = *(const float4*)&sU[2 * DD + j * 4];
        const float4 u3 = *(const float4*)&sU[3 * DD + j * 4];
        const float4 s0 = *(const float4*)&sS[0 * DD + j * 4];
        const float4 s1 = *(const float4*)&sS[1 * DD + j * 4];
        const float4 s2 = *(const float4*)&sS[2 * DD + j * 4];
        const float4 s3 = *(const float4*)&sS[3 * DD + j * 4];
        const float4 uu = *(const float4*)&sUu[j * 4];
        const float rist = __builtin_amdgcn_rcpf(sI[0] + sI[1] + sI[2] + sI[3]);
        vr.x = uu.x + (u0.x + u1.x + u2.x + u3.x) * rist + (s0.x + s1.x + s2.x + s3.x);
        vr.y = uu.y + (u0.y + u1.y + u2.y + u3.y) * rist + (s0.y + s1.y + s2.y + s3.y);
        vr.z = uu.z + (u0.z + u1.z + u2.z + u3.z) * rist + (s0.z + s1.z + s2.z + s3.z);
        vr.w = uu.w + (u0.w + u1.w + u2.w + u3.w) * rist + (s0.w + s1.w + s2.w + s3.w);
    }

    // ---- scoring from prefetched registers ----
#pragma unroll
    for (int i = 0; i < 7; i++) {
        const int ts = i * 16 + gg;
        float s = wv[i].x * vr.x + wv[i].y * vr.y + wv[i].z * vr.z + wv[i].w * vr.w;
        s += __shfl_xor(s, 1); s += __shfl_xor(s, 2);
        s += __shfl_xor(s, 4); s += __shfl_xor(s, 8);
        if (j == 0 && ts < NT) sOut[ts] = s + sB[ts];
    }
    __syncthreads();   // barrier 2: sOut staging
    if (tid < NT) out[b * NT + tid] = sOut[tid];
}

// ===========================================================================
extern "C" void kernel_launch(void* const* d_in, const int* in_sizes, int n_in,
                              void* d_out, int out_size, void* d_ws, size_t ws_size,
                              hipStream_t stream)
{
    const int* user_ids        = (const int*)d_in[0];
    const int* item_seq_ids    = (const int*)d_in[1];
    const int* target_item_ids = (const int*)d_in[2];
    const float* user_tab      = (const float*)d_in[3];
    const float* item_tab      = (const float*)d_in[4];
    const float* W2_tab        = (const float*)d_in[5];
    const float* b2_tab        = (const float*)d_in[6];
    const float* fg_item_W     = (const float*)d_in[7];
    const float* fg_item_b     = (const float*)d_in[8];
    const float* fg_user_W     = (const float*)d_in[9];
    const float* fg_user_b     = (const float*)d_in[10];
    const float* igi           = (const float*)d_in[11];
    const float* igu           = (const float*)d_in[12];
    float* out = (float*)d_out;

    float* ufg_ws = (float*)d_ws;                       // [4096][64] f32
    float* t2_ws  = ufg_ws + NB * DD;                   // [4096][64] f32
    unsigned short* wiB_ws = (unsigned short*)(t2_ws + NB * DD);  // [64][64] bf16

    k0_user<<<257, 256, 0, stream>>>(user_ids, user_tab, fg_user_W, fg_user_b,
                                     fg_item_b, igu, fg_item_W,
                                     ufg_ws, t2_ws, wiB_ws);
    k1_fused<<<NB, 256, 0, stream>>>(user_ids, item_seq_ids, target_item_ids,
                                     user_tab, item_tab, W2_tab, b2_tab,
                                     wiB_ws, igi, ufg_ws, t2_ws, out);
}

// Round 12
// 154.945 us; speedup vs baseline: 1.0752x; 1.0011x over previous
//
#include <hip/hip_runtime.h>

// Problem constants
#define DD 64
#define LL 50
#define NB 4096
#define NT 100

typedef __attribute__((ext_vector_type(8))) __bf16 bf16x8;
typedef __attribute__((ext_vector_type(4))) float f32x4;

__device__ __forceinline__ float sigmoidf_(float x) {
    // v_rcp_f32 (~1ulp) instead of precise-division sequence
    return __builtin_amdgcn_rcpf(1.0f + __expf(-x));
}
// round-half-up f32->bf16, pack two into one u32 (hi -> upper 16)  [k0 path]
__device__ __forceinline__ unsigned pack_bf16(float hi, float lo) {
    union { float f; unsigned u; } a, b;
    a.f = hi; b.f = lo;
    return ((a.u + 0x8000u) & 0xffff0000u) | ((b.u + 0x8000u) >> 16);
}
__device__ __forceinline__ uint4 cvt8u(const float* f) {
    uint4 r;
    r.x = pack_bf16(f[1], f[0]);
    r.y = pack_bf16(f[3], f[2]);
    r.z = pack_bf16(f[5], f[4]);
    r.w = pack_bf16(f[7], f[6]);
    return r;
}
__device__ __forceinline__ bf16x8 cvt8(const float* f) {
    return __builtin_bit_cast(bf16x8, cvt8u(f));
}
// HW packed RNE convert: dst.lo = bf16(lo), dst.hi = bf16(hi)  [k1 path]
__device__ __forceinline__ unsigned cvtpk(float lo, float hi) {
    unsigned r;
    asm("v_cvt_pk_bf16_f32 %0, %1, %2" : "=v"(r) : "v"(lo), "v"(hi));
    return r;
}
__device__ __forceinline__ bf16x8 cvt8f(const float* f) {
    uint4 r;
    r.x = cvtpk(f[0], f[1]);
    r.y = cvtpk(f[2], f[3]);
    r.z = cvtpk(f[4], f[5]);
    r.w = cvtpk(f[6], f[7]);
    return __builtin_bit_cast(bf16x8, r);
}
// async global->LDS: wave-uniform LDS base + lane*size (gfx950)
__device__ __forceinline__ void glds16(const float* g, float* l) {
    __builtin_amdgcn_global_load_lds(
        (const __attribute__((address_space(1))) void*)g,
        (__attribute__((address_space(3))) void*)l, 16, 0, 0);
}
__device__ __forceinline__ void glds4(const float* g, float* l) {
    __builtin_amdgcn_global_load_lds(
        (const __attribute__((address_space(1))) void*)g,
        (__attribute__((address_space(3))) void*)l, 4, 0, 0);
}

// ===========================================================================
// K0: blocks 0..255: batched user GEMM (16 users/block, 2 waves: wave 0 does
//     ni 0..3 (fg_user_W), wave 1 does ni 4..7 (inst_gate_user)).
//     block 256: pack fg_item_W -> bf16 row-major (k1 reads frags directly).
// ===========================================================================
__global__ __launch_bounds__(128) void k0_user(
    const int* __restrict__ uid_g, const float* __restrict__ user_table,
    const float* __restrict__ Wu, const float* __restrict__ bu,
    const float* __restrict__ bi, const float* __restrict__ igu,
    const float* __restrict__ Wi,
    float* __restrict__ ufg_ws, float* __restrict__ t2_ws,
    unsigned short* __restrict__ wiB_ws)
{
    if (blockIdx.x == 256) {   // Wi -> bf16 pack (one wave only)
        if (threadIdx.x >= 64) return;
        const int n = threadIdx.x;
        float tmp[64];
#pragma unroll
        for (int c4 = 0; c4 < 16; c4++)
            *(float4*)&tmp[c4 * 4] = *(const float4*)(Wi + n * DD + c4 * 4);
#pragma unroll
        for (int ch = 0; ch < 8; ch++)
            *(uint4*)(wiB_ws + n * DD + ch * 8) = cvt8u(tmp + ch * 8);
        return;
    }

    const int lane = threadIdx.x & 63;
    const int wv = threadIdx.x >> 6;         // wave 0: ni 0..3, wave 1: ni 4..7
    const int c = lane & 15, q = lane >> 4;
    const int uid = uid_g[blockIdx.x * 16 + c];
    const float* urow = user_table + (size_t)uid * DD;

    bf16x8 af[2];
#pragma unroll
    for (int kf = 0; kf < 2; kf++) {
        float tmp[8];
        *(float4*)&tmp[0] = *(const float4*)(urow + kf * 32 + q * 8);
        *(float4*)&tmp[4] = *(const float4*)(urow + kf * 32 + q * 8 + 4);
        af[kf] = cvt8(tmp);
    }

#pragma unroll
    for (int ni0 = 0; ni0 < 4; ni0++) {
        const int ni = wv * 4 + ni0;
        f32x4 a = {0.f, 0.f, 0.f, 0.f};
#pragma unroll
        for (int kf = 0; kf < 2; kf++) {
            const int k0 = kf * 32 + q * 8;
            float tmp[8];
            if (ni < 4) {
                const float* src = Wu + (ni * 16 + c) * DD + k0;
                *(float4*)&tmp[0] = *(const float4*)src;
                *(float4*)&tmp[4] = *(const float4*)(src + 4);
            } else {
                const int l = ni * 16 + c - 64;
#pragma unroll
                for (int jj = 0; jj < 8; jj++)
                    tmp[jj] = (l < LL) ? igu[(k0 + jj) * LL + l] : 0.f;
            }
            a = __builtin_amdgcn_mfma_f32_16x16x32_bf16(af[kf], cvt8(tmp), a, 0, 0, 0);
        }
        const int n = ni * 16 + c;
#pragma unroll
        for (int reg = 0; reg < 4; reg++) {
            const int bo = blockIdx.x * 16 + q * 4 + reg;
            if (n < DD)           ufg_ws[bo * DD + n] = a[reg] + bu[n] + bi[n];
            else if (n < DD + LL) t2_ws[bo * DD + (n - DD)] = a[reg];
        }
    }
}

// ===========================================================================
// K1F v3 (best verified: 41.5us): fused union + scoring; WAVE-DECOUPLED
//   phases A/B.  Wave w only touches item rows w*16..w*16+15 -> item tile is
//   wave-PRIVATE.  Each wave: issue own 4 glds16 + W2 regs + t2 float4 +
//   wb/scalars, asm s_waitcnt vmcnt(0) + sched_barrier(0) (rule 18), then
//   phase B independently.  2 barriers: cross-wave reduce, sOut staging.
// ===========================================================================
__global__ __launch_bounds__(256, 4) void k1_fused(
    const int* __restrict__ uid_g, const int* __restrict__ iid_g,
    const int* __restrict__ tgt_g,
    const float* __restrict__ user_table, const float* __restrict__ item_table,
    const float* __restrict__ W2, const float* __restrict__ b2,
    const unsigned short* __restrict__ wiB, const float* __restrict__ igi,
    const float* __restrict__ ufg_ws, const float* __restrict__ t2_ws,
    float* __restrict__ out)
{
    const int tid = threadIdx.x;
    const int lane = tid & 63;
    const int w = tid >> 6;                 // wave id 0..3 == union mi
    const int c = lane & 15, q = lane >> 4;
    const int j = tid & 15, gg = tid >> 4;  // scoring: 16 groups of 16 lanes
    const int b = blockIdx.x;

    __shared__ __align__(16) float sE[4][16 * DD];  // wave-private item quadrants
    __shared__ __align__(16) float sB[128];         // b2 staged
    __shared__ __align__(16) float sUu[DD];         // user row
    __shared__ __align__(16) float sU[4 * DD];      // per-wave unum partials
    __shared__ __align__(16) float sS[4 * DD];      // per-wave sip partials
    __shared__ float sI[4];                         // per-wave isum partials
    __shared__ float sOut[112];

    const int* iidp = iid_g + b * LL;
    const int* tgtp = tgt_g + b * NT;
    float* sEw = sE[w];

    // ---- item ids for THIS wave's 16 rows (clamped) ----
    int iid4[4];
#pragma unroll
    for (int s = 0; s < 4; s++) {
        const int r = w * 16 + 4 * s + (lane >> 4);
        iid4[s] = iidp[r < LL ? r : LL - 1];
    }
    // ---- tgt ids (group-major, for W2 prefetch) ----
    int tt[7];
#pragma unroll
    for (int i = 0; i < 7; i++) {
        const int ts = i * 16 + gg;             // 0..111 (100..111 = pad)
        tt[i] = tgtp[ts < NT ? ts : NT - 1];
    }

    // ---- async item gather into own quadrant: local rows 4s..4s+3, 16B
    //      chunks XOR-swizzled by (local_row & 7) ----
#pragma unroll
    for (int s = 0; s < 4; s++) {
        const int rl = 4 * s + (lane >> 4);
        const int j2 = (lane & 15) ^ (rl & 7);
        glds16(item_table + (size_t)iid4[s] * DD + j2 * 4, sEw + s * 256);
    }

    // ---- W2 prefetch to regs (pinned before the waitcnt below) ----
    float4 wv[7];
#pragma unroll
    for (int i = 0; i < 7; i++)
        wv[i] = *(const float4*)(W2 + (size_t)tt[i] * DD + j * 4);

    // ---- small staged loads, spread across waves ----
    if (w == 1) {
        const int uid = uid_g[b];
        glds4(user_table + (size_t)uid * DD + lane, sUu);
    }
    if (w == 2) {
        const int tb = lane < NT ? lane : NT - 1;
        glds4(b2 + tgtp[tb], sB);
    }
    if (w == 3) {
        const int sl = 64 + lane;
        const int tb = sl < NT ? sl : NT - 1;
        glds4(b2 + tgtp[tb], sB + 64);
    }

    // ---- per-b scalars + t2 slice (float4, no LDS round-trip) ----
    float ufg4[4], igi4[4];
#pragma unroll
    for (int ni = 0; ni < 4; ni++) {
        ufg4[ni] = ufg_ws[b * DD + ni * 16 + c];
        igi4[ni] = igi[ni * 16 + c];
    }
    const float4 t2v = *(const float4*)(t2_ws + b * DD + w * 16 + q * 4);
    float t2a[4] = {t2v.x, t2v.y, t2v.z, t2v.w};

    // ---- wb frags (8 KB table, L2-hot) ----
    bf16x8 wb[4][2];
#pragma unroll
    for (int ni = 0; ni < 4; ni++)
#pragma unroll
        for (int kf = 0; kf < 2; kf++)
            wb[ni][kf] = __builtin_bit_cast(bf16x8,
                *(const uint4*)(wiB + (ni * 16 + c) * DD + kf * 32 + q * 8));

    // ---- wave-local drain: own glds + all reg loads complete; no barrier ----
    asm volatile("s_waitcnt vmcnt(0)" ::: "memory");
    __builtin_amdgcn_sched_barrier(0);

    // ---- A-frags from own quadrant (deswizzled), invalid rows zeroed ----
    bf16x8 ea[2];
    {
        const int grow = w * 16 + c;
        const float* rowp = sEw + c * DD;
        const int s7 = c & 7;
#pragma unroll
        for (int kf = 0; kf < 2; kf++) {
            float tmp[8];
            const int ch0 = (kf * 8 + 2 * q) ^ s7;
            const int ch1 = (kf * 8 + 2 * q + 1) ^ s7;
            *(float4*)&tmp[0] = *(const float4*)(rowp + ch0 * 4);
            *(float4*)&tmp[4] = *(const float4*)(rowp + ch1 * 4);
            if (grow >= LL) {
#pragma unroll
                for (int i = 0; i < 8; i++) tmp[i] = 0.f;
            }
            ea[kf] = cvt8f(tmp);
        }
    }

    // ---- union MFMA + fused per-reg epilogue (all reads wave-private) ----
    float unum[4] = {0.f, 0.f, 0.f, 0.f};
    float sip[4]  = {0.f, 0.f, 0.f, 0.f};
    float isum = 0.f;
    {
        f32x4 acc[4];
#pragma unroll
        for (int ni = 0; ni < 4; ni++) {
            f32x4 a = {0.f, 0.f, 0.f, 0.f};
            a = __builtin_amdgcn_mfma_f32_16x16x32_bf16(ea[0], wb[ni][0], a, 0, 0, 0);
            a = __builtin_amdgcn_mfma_f32_16x16x32_bf16(ea[1], wb[ni][1], a, 0, 0, 0);
            acc[ni] = a;
        }
#pragma unroll
        for (int reg = 0; reg < 4; reg++) {
            const int lrl = q * 4 + reg;            // local row in quadrant
            const int valid = (w * 16 + lrl < LL);
            const int s7 = lrl & 7;
            float gd[4];
            float t1 = 0.f;
#pragma unroll
            for (int ni = 0; ni < 4; ni++) {
                const int phys = (4 * ni + (c >> 2)) ^ s7;
                const float ev = sEw[lrl * DD + phys * 4 + (c & 3)];
                const float e = valid ? ev : 0.f;
                const float g = sigmoidf_(acc[ni][reg] + ufg4[ni]);
                gd[ni] = e * g;
                t1 += gd[ni] * igi4[ni];
                sip[ni] += e;
            }
            t1 += __shfl_xor(t1, 1); t1 += __shfl_xor(t1, 2);
            t1 += __shfl_xor(t1, 4); t1 += __shfl_xor(t1, 8);
            const float inst = valid ? sigmoidf_(t1 + t2a[reg]) : 0.f;
            isum += inst;
#pragma unroll
            for (int ni = 0; ni < 4; ni++)
                unum[ni] += gd[ni] * inst;
        }
    }

    // intra-wave: sum over q groups, then pick ni == q -> value for d = lane
#pragma unroll
    for (int ni = 0; ni < 4; ni++) {
        unum[ni] += __shfl_xor(unum[ni], 16); unum[ni] += __shfl_xor(unum[ni], 32);
        sip[ni]  += __shfl_xor(sip[ni], 16);  sip[ni]  += __shfl_xor(sip[ni], 32);
    }
    isum += __shfl_xor(isum, 16); isum += __shfl_xor(isum, 32);

    const float un = (q == 0) ? unum[0] : (q == 1) ? unum[1] : (q == 2) ? unum[2] : unum[3];
    const float si = (q == 0) ? sip[0]  : (q == 1) ? sip[1]  : (q == 2) ? sip[2]  : sip[3];
    sU[w * DD + lane] = un;
    sS[w * DD + lane] = si;
    if (lane == 0) sI[w] = isum;
    __syncthreads();   // barrier 1: cross-wave reduce (also orders sUu/sB)

    // ---- redundant all-thread reduce -> vr (user-vector slice dims j*4..) ----
    float4 vr;
    {
        const float4 u0 = *(const float4*)&sU[0 * DD + j * 4];
        const float4 u1 = *(const float4*)&sU[1 * DD + j * 4];
        const float4 u2 = *(const float4*)&sU[2 * DD + j * 4];
        const float4 u3 = *(const float4*)&sU[3 * DD + j * 4];
        const float4 s0 = *(const float4*)&sS[0 * DD + j * 4];
        const float4 s1 = *(const float4*)&sS[1 * DD + j * 4];
        const float4 s2 = *(const float4*)&sS[2 * DD + j * 4];
        const float4 s3 = *(const float4*)&sS[3 * DD + j * 4];
        const float4 uu = *(const float4*)&sUu[j * 4];
        const float rist = __builtin_amdgcn_rcpf(sI[0] + sI[1] + sI[2] + sI[3]);
        vr.x = uu.x + (u0.x + u1.x + u2.x + u3.x) * rist + (s0.x + s1.x + s2.x + s3.x);
        vr.y = uu.y + (u0.y + u1.y + u2.y + u3.y) * rist + (s0.y + s1.y + s2.y + s3.y);
        vr.z = uu.z + (u0.z + u1.z + u2.z + u3.z) * rist + (s0.z + s1.z + s2.z + s3.z);
        vr.w = uu.w + (u0.w + u1.w + u2.w + u3.w) * rist + (s0.w + s1.w + s2.w + s3.w);
    }

    // ---- scoring from prefetched registers ----
#pragma unroll
    for (int i = 0; i < 7; i++) {
        const int ts = i * 16 + gg;
        float s = wv[i].x * vr.x + wv[i].y * vr.y + wv[i].z * vr.z + wv[i].w * vr.w;
        s += __shfl_xor(s, 1); s += __shfl_xor(s, 2);
        s += __shfl_xor(s, 4); s += __shfl_xor(s, 8);
        if (j == 0 && ts < NT) sOut[ts] = s + sB[ts];
    }
    __syncthreads();   // barrier 2: sOut staging
    if (tid < NT) out[b * NT + tid] = sOut[tid];
}

// ===========================================================================
extern "C" void kernel_launch(void* const* d_in, const int* in_sizes, int n_in,
                              void* d_out, int out_size, void* d_ws, size_t ws_size,
                              hipStream_t stream)
{
    const int* user_ids        = (const int*)d_in[0];
    const int* item_seq_ids    = (const int*)d_in[1];
    const int* target_item_ids = (const int*)d_in[2];
    const float* user_tab      = (const float*)d_in[3];
    const float* item_tab      = (const float*)d_in[4];
    const float* W2_tab        = (const float*)d_in[5];
    const float* b2_tab        = (const float*)d_in[6];
    const float* fg_item_W     = (const float*)d_in[7];
    const float* fg_item_b     = (const float*)d_in[8];
    const float* fg_user_W     = (const float*)d_in[9];
    const float* fg_user_b     = (const float*)d_in[10];
    const float* igi           = (const float*)d_in[11];
    const float* igu           = (const float*)d_in[12];
    float* out = (float*)d_out;

    float* ufg_ws = (float*)d_ws;                       // [4096][64] f32
    float* t2_ws  = ufg_ws + NB * DD;                   // [4096][64] f32
    unsigned short* wiB_ws = (unsigned short*)(t2_ws + NB * DD);  // [64][64] bf16

    k0_user<<<257, 128, 0, stream>>>(user_ids, user_tab, fg_user_W, fg_user_b,
                                     fg_item_b, igu, fg_item_W,
                                     ufg_ws, t2_ws, wiB_ws);
    k1_fused<<<NB, 256, 0, stream>>>(user_ids, item_seq_ids, target_item_ids,
                                     user_tab, item_tab, W2_tab, b2_tab,
                                     wiB_ws, igi, ufg_ws, t2_ws, out);
}